// Round 2
// baseline (438.342 us; speedup 1.0000x reference)
//
#include <hip/hip_runtime.h>
#include <math.h>

#define NB 16      // batch
#define NO 128     // output channels
#define ND 64      // manifold dim
#define NN 30      // grid side
#define NM 27000   // NN^3
#define PROW 32    // k-padded row length
#define PPLANE 960 // 30*PROW
#define PML 28800  // 30*PPLANE  (padded points per (b,o))

typedef _Float16 half8 __attribute__((ext_vector_type(8)));
typedef _Float16 half4 __attribute__((ext_vector_type(4)));
typedef float    f32x4 __attribute__((ext_vector_type(4)));

// ---------------------------------------------------------------------------
__device__ __forceinline__ float asinh_fast(float t) {
    return __logf(t + __builtin_amdgcn_sqrtf(t * t + 1.0f));
}

__device__ __forceinline__ float gyro_dist(float x2, float dp, float da,
                                           float p2, float pa, float an) {
    float beta  = 1.0f - p2;
    float alpha = 1.0f - 2.0f * dp + x2;
    float den   = fmaxf(1.0f - 2.0f * dp + p2 * x2, 1e-15f);
    float rden  = __builtin_amdgcn_rcpf(den);
    float sc    = (beta * da - alpha * pa) * rden;
    float dn2   = fmaxf((alpha * alpha * p2 - 2.0f * alpha * beta * dp +
                         beta * beta * x2) * (rden * rden), 1e-15f);
    float denom = fmaxf((1.0f - dn2) * an, 1e-15f);
    float t     = 2.0f * sc * __builtin_amdgcn_rcpf(denom);
    return asinh_fast(t);
}

// Param algebra collapsed to scalars of S = sum_d w[o][d]^2 (exact rewrite
// of the reference expmap0/project/transp0 chain).
__device__ __forceinline__ void param_scalars(float S, float bb,
                                              float* fp_o, float* p2_o,
                                              float* betaC_o, float* pa_o,
                                              float* an_o) {
    float sq  = sqrtf(S);
    float un  = fmaxf(fabsf(bb) * sq, 1e-15f);
    float t1  = tanhf(fminf(un, 15.0f));
    float sc1 = t1 / un;
    float gn  = fmaxf(t1, 1e-15f);
    float sc2 = (gn > 0.996f) ? (0.996f / gn) : 1.0f;
    float fp  = bb * sc1 * sc2;
    float p2  = fp * fp * S;
    float betaC = fmaxf(1.0f - p2, 1e-15f);
    *fp_o = fp; *p2_o = p2; *betaC_o = betaC;
    *pa_o = fp * betaC * S;
    *an_o = fmaxf(betaC * sq, 1e-15f);
}

// dist at origin; first wave computes, result valid after __syncthreads()
__device__ __forceinline__ void dist0_wave(const float* __restrict__ w,
                                           const float* __restrict__ bias,
                                           int o, int tid, float* out_lds) {
    if (tid < 64) {
        float v = w[o * ND + tid];
        float s = v * v;
#pragma unroll
        for (int off = 32; off > 0; off >>= 1) s += __shfl_xor(s, off, 64);
        if (tid == 0) {
            float fp, p2, betaC, pa, an;
            param_scalars(s, bias[o], &fp, &p2, &betaC, &pa, &an);
            float dn2   = fmaxf(p2, 1e-15f);
            float denom = fmaxf((1.0f - dn2) * an, 1e-15f);
            *out_lds = asinh_fast(-2.0f * pa * __builtin_amdgcn_rcpf(denom));
        }
    }
}

// ---------------------------------------------------------------------------
// Kernel 0: per-o params -> global (f16 B-fragments + f32 scalars).
// Fragment layout matches the dist kernel's per-lane read:
//   frag[(ot8*2+h)*64 + (o&15) + 16*q] holds B[k=h*32+q*8+jj][o]
// ---------------------------------------------------------------------------
__global__ __launch_bounds__(128) void gyro_params_k(
    const float* __restrict__ w, const float* __restrict__ bias,
    _Float16* __restrict__ pfg, _Float16* __restrict__ afg,
    float* __restrict__ p2g, float* __restrict__ pag,
    float* __restrict__ ang) {
    int o = threadIdx.x;            // 128 threads, one o each
    const float* wr = w + o * ND;
    float bb = bias[o];
    float S = 0.0f;
    for (int d = 0; d < ND; ++d) S += wr[d] * wr[d];
    float fp, p2, betaC, pa, an;
    param_scalars(S, bb, &fp, &p2, &betaC, &pa, &an);
    p2g[o] = p2; pag[o] = pa; ang[o] = an;

    half8* pf8 = (half8*)pfg;
    half8* af8 = (half8*)afg;
    int ot8 = o >> 4, j = o & 15;
#pragma unroll
    for (int h = 0; h < 2; ++h)
#pragma unroll
        for (int q = 0; q < 4; ++q) {
            int d0i = h * 32 + q * 8;
            half8 hp, ha;
#pragma unroll
            for (int jj = 0; jj < 8; ++jj) {
                float wv = wr[d0i + jj];
                hp[jj] = (_Float16)(wv * fp);
                ha[jj] = (_Float16)(wv * betaC);
            }
            pf8[(ot8 * 2 + h) * 64 + j + 16 * q] = hp;
            af8[(ot8 * 2 + h) * 64 + j + 16 * q] = ha;
        }
}

// ---------------------------------------------------------------------------
// Kernel 1: dist -> f16 k-padded tmp [b][o][row<900>][32], storing the
// 3-tap K-SUM (k-1,k,k+1) instead of raw dist. Each lane holds 4 consecutive
// padded-m (= 4 consecutive k within a 32-padded row), so the k-sum needs
// only wave shuffles:
//   left  of quad q elem 0 = lane-16's elem 3   (q>0)
//                          = lane+48's dv[mt-1][3] (q==0, odd mt)
//                          = d0                  (q==0, even mt: kcol==0)
//   right of quad q elem 3 = lane+16's elem 0   (q<3)
//                          = lane-48's dv[mt+1][0] (q==3, even mt)
//                          = don't-care (kcol==31 pad) (q==3, odd mt)
// Sum is done in f32 BEFORE f16 quantization (slightly better precision than
// the old box-side k-pass over f16 values).
// ---------------------------------------------------------------------------
__global__ __launch_bounds__(256) void gyro_dist_mfma_h(
    const float* __restrict__ x,
    const _Float16* __restrict__ pfg, const _Float16* __restrict__ afg,
    const float* __restrict__ p2g, const float* __restrict__ pag,
    const float* __restrict__ ang,
    _Float16* __restrict__ tmp) {
    __shared__ __align__(16) half8 xf[8 * 64];   // 8 KB
    __shared__ float x2p[64 * 8];
    __shared__ __align__(16) float x2_s[64];

    const int tid = threadIdx.x;
    const int mp0 = blockIdx.x * 64;
    const int b   = blockIdx.y;
    const int lane = tid & 63, wid = tid >> 6;

    // prefetch B fragments into registers (L2-hot, coalesced 16B/lane)
    const half8* pf8 = (const half8*)pfg;
    const half8* af8 = (const half8*)afg;
    half8 bp[2][2], ba[2][2];
#pragma unroll
    for (int ot = 0; ot < 2; ++ot)
#pragma unroll
        for (int h = 0; h < 2; ++h) {
            int idx = ((wid * 2 + ot) * 2 + h) * 64 + lane;
            bp[ot][h] = pf8[idx];
            ba[ot][h] = af8[idx];
        }

    // stage x tile (f32 -> f16 fragments) + |x|^2 partials
#pragma unroll
    for (int n = 0; n < 2; ++n) {
        int s = tid + n * 256;
        int f = s >> 6, l = s & 63;
        int mt = f >> 1, h = f & 1;
        int mloc = mt * 16 + (l & 15);
        int quad = l >> 4;
        int k0 = h * 32 + quad * 8;
        int gmp = mp0 + mloc;
        int kcol = gmp & 31;
        int row  = gmp >> 5;
        half8 hv;
        float part = 0.0f;
        if (kcol < 30) {
            int gm = row * 30 + kcol;
            const float4* src = (const float4*)(x + ((size_t)gm * NB + b) * ND + k0);
            float4 v0 = src[0], v1 = src[1];
            float vv[8] = {v0.x, v0.y, v0.z, v0.w, v1.x, v1.y, v1.z, v1.w};
#pragma unroll
            for (int jj = 0; jj < 8; ++jj) {
                hv[jj] = (_Float16)vv[jj];
                part += vv[jj] * vv[jj];
            }
        } else {
#pragma unroll
            for (int jj = 0; jj < 8; ++jj) hv[jj] = (_Float16)0.0f;
        }
        xf[f * 64 + l] = hv;
        x2p[mloc * 8 + h * 4 + quad] = part;
    }
    __syncthreads();
    if (tid < 64) {
        float s = 0.0f;
#pragma unroll
        for (int r = 0; r < 8; ++r) s += x2p[tid * 8 + r];
        x2_s[tid] = s;
    }
    __syncthreads();

    // MFMA: 4 m-tiles x 2 o-tiles x {p,a} x 2 k-halves
    f32x4 accp[4][2], acca[4][2];
#pragma unroll
    for (int mt = 0; mt < 4; ++mt)
#pragma unroll
        for (int ot = 0; ot < 2; ++ot) {
            accp[mt][ot] = (f32x4)0.0f;
            acca[mt][ot] = (f32x4)0.0f;
        }
#pragma unroll
    for (int h = 0; h < 2; ++h) {
        half8 afr[4];
#pragma unroll
        for (int mt = 0; mt < 4; ++mt) afr[mt] = xf[(mt * 2 + h) * 64 + lane];
#pragma unroll
        for (int mt = 0; mt < 4; ++mt)
#pragma unroll
            for (int ot = 0; ot < 2; ++ot) {
                accp[mt][ot] = __builtin_amdgcn_mfma_f32_16x16x32_f16(
                    afr[mt], bp[ot][h], accp[mt][ot], 0, 0, 0);
                acca[mt][ot] = __builtin_amdgcn_mfma_f32_16x16x32_f16(
                    afr[mt], ba[ot][h], acca[mt][ot], 0, 0, 0);
            }
    }

    // epilogue: gyro dist per element in f32, in-register 3-tap k-sum via
    // shuffles, then f16 store of 4 consecutive padded-m (8B).
    const int lo = lane & 15, quad = lane >> 4;
    const size_t obase = (size_t)(b * NO) * PML;
#pragma unroll
    for (int ot = 0; ot < 2; ++ot) {
        const int o = wid * 32 + ot * 16 + lo;
        const float P2 = p2g[o], PA = pag[o], AN = ang[o];
        const float denom0 = fmaxf((1.0f - fmaxf(P2, 1e-15f)) * AN, 1e-15f);
        const float d0 = asinh_fast(-2.0f * PA * __builtin_amdgcn_rcpf(denom0));
        float dv[4][4];
#pragma unroll
        for (int mt = 0; mt < 4; ++mt) {
            const int mb = mt * 16 + quad * 4;
            float4 x2v = *(const float4*)&x2_s[mb];
            dv[mt][0] = gyro_dist(x2v.x, accp[mt][ot][0], acca[mt][ot][0], P2, PA, AN);
            dv[mt][1] = gyro_dist(x2v.y, accp[mt][ot][1], acca[mt][ot][1], P2, PA, AN);
            dv[mt][2] = gyro_dist(x2v.z, accp[mt][ot][2], acca[mt][ot][2], P2, PA, AN);
            dv[mt][3] = gyro_dist(x2v.w, accp[mt][ot][3], acca[mt][ot][3], P2, PA, AN);
        }
#pragma unroll
        for (int mt = 0; mt < 4; ++mt) {
            // all lanes execute the shuffles; invalid-source lanes are
            // selected away below (quad/mt conditions are exact)
            float tl = __shfl_up(dv[mt][3], 16);      // lane-16: prev quad e3
            float tr = __shfl_down(dv[mt][0], 16);    // lane+16: next quad e0
            float L, R;
            if (mt & 1) {
                float tl2 = __shfl_down(dv[mt - 1][3], 48); // lane+48 (quad0 only)
                L = (quad == 0) ? tl2 : tl;
                R = (quad == 3) ? d0 : tr;            // kcol==31 pad: don't-care
            } else {
                float tr2 = __shfl_up(dv[mt + 1][0], 48);   // lane-48 (quad3 only)
                L = (quad == 0) ? d0 : tl;            // kcol==0: left pad = d0
                R = (quad == 3) ? tr2 : tr;
            }
            half4 hv;
            hv[0] = (_Float16)(L + dv[mt][0] + dv[mt][1]);
            hv[1] = (_Float16)(dv[mt][0] + dv[mt][1] + dv[mt][2]);
            hv[2] = (_Float16)(dv[mt][1] + dv[mt][2] + dv[mt][3]);
            hv[3] = (_Float16)(dv[mt][2] + dv[mt][3] + R);
            *(half4*)(tmp + obase + (size_t)o * PML + (mp0 + mt * 16 + quad * 4)) = hv;
        }
    }
}

// ---------------------------------------------------------------------------
// Kernel 2: 3x3x3 box sum, but tmp now holds K-PRE-SUMMED values, so only the
// j-pass and i-pass remain (LDS ops per quad 10 -> 8, barriers 6 -> 4).
// OOB planes / j-pad rows are the k-sum of an all-d0 row = 3*d0 per col.
// Pad cols (k=30,31) carry junk that stays in their own column (j/i passes
// are column-pure) and is never stored.
// ---------------------------------------------------------------------------
__global__ __launch_bounds__(256) void gyro_box3d_h(
    const _Float16* __restrict__ tmp, float* __restrict__ dst,
    const float* __restrict__ w, const float* __restrict__ bias) {
    __shared__ __align__(16) float vin[10 * PPLANE];   // 38.4 KB
    __shared__ float d0sh;

    const int tid = threadIdx.x;
    const int i0  = blockIdx.x * 8;
    const int o   = blockIdx.y;
    const int b   = blockIdx.z;
    const int bo  = b * NO + o;

    dist0_wave(w, bias, o, tid, &d0sh);
    __syncthreads();
    const float d0 = d0sh;
    const float T3 = 3.0f * d0;          // k-sum of an all-d0 row
    float4* vin4 = (float4*)vin;

    // load 10 padded planes (120 x half8 each); OOB plane -> 3*d0
    const half8* tsrc = (const half8*)(tmp + (size_t)bo * PML);
    for (int idx = tid; idx < 1200; idx += 256) {
        int sl = idx / 120, r8 = idx - sl * 120;
        int ip = i0 - 1 + sl;
        float f[8];
        if (ip >= 0 && ip < NN) {
            half8 hv = tsrc[ip * 120 + r8];
#pragma unroll
            for (int jj = 0; jj < 8; ++jj) f[jj] = (float)hv[jj];
        } else {
#pragma unroll
            for (int jj = 0; jj < 8; ++jj) f[jj] = T3;
        }
        int o4 = (sl * PPLANE + r8 * 8) >> 2;
        float4 v0; v0.x = f[0]; v0.y = f[1]; v0.z = f[2]; v0.w = f[3];
        float4 v1; v1.x = f[4]; v1.y = f[5]; v1.z = f[6]; v1.w = f[7];
        vin4[o4] = v0; vin4[o4 + 1] = v1;
    }
    __syncthreads();

    float4 st[10];

    // ---- j-pass (in-place) ----
#pragma unroll
    for (int n = 0; n < 10; ++n) {
        int q = tid + n * 256;
        if (q < 2400) {
            int rem = q % 240;
            int j = rem >> 3;
            float4 cc = vin4[q];
            float4 up, dn;
            if (j == 0)  { up.x = T3; up.y = T3; up.z = T3; up.w = T3; }
            else         up = vin4[q - 8];
            if (j == 29) { dn.x = T3; dn.y = T3; dn.z = T3; dn.w = T3; }
            else         dn = vin4[q + 8];
            float4 s;
            s.x = cc.x + up.x + dn.x; s.y = cc.y + up.y + dn.y;
            s.z = cc.z + up.z + dn.z; s.w = cc.w + up.w + dn.w;
            st[n] = s;
        }
    }
    __syncthreads();
#pragma unroll
    for (int n = 0; n < 10; ++n) {
        int q = tid + n * 256;
        if (q < 2400) vin4[q] = st[n];
    }
    __syncthreads();

    // ---- i-pass + store (unpadded f32 output, 8B-aligned float2 stores) ----
    const int nout = (NN - i0 < 8) ? (NN - i0) : 8;
    for (int q = tid; q < nout * 240; q += 256) {
        int pl = q / 240, rem = q - pl * 240;
        int j = rem >> 3, c = rem & 7;
        int o4 = (pl + 1) * 240 + rem;
        float4 a = vin4[o4 - 240], m = vin4[o4], e = vin4[o4 + 240];
        float4 s;
        s.x = a.x + m.x + e.x; s.y = a.y + m.y + e.y;
        s.z = a.z + m.z + e.z; s.w = a.w + m.w + e.w;
        int i = i0 + pl;
        float* g = dst + (size_t)bo * NM + i * 900 + j * 30 + c * 4;
        float2 lo2; lo2.x = s.x; lo2.y = s.y;
        *(float2*)g = lo2;
        if (c < 7) {                      // k=28..29 only for the last quad
            float2 hi2; hi2.x = s.z; hi2.y = s.w;
            *(float2*)(g + 2) = hi2;
        }
    }
}

extern "C" void kernel_launch(void* const* d_in, const int* in_sizes, int n_in,
                              void* d_out, int out_size, void* d_ws, size_t ws_size,
                              hipStream_t stream) {
    const float* x    = (const float*)d_in[0];   // (M, B, D)
    const float* w    = (const float*)d_in[1];   // (O, D)
    const float* bias = (const float*)d_in[2];   // (O, 1)
    float* out = (float*)d_out;                  // (B, O, N, N, N)

    // ws layout: pf 32KB-half | af | p2/pa/an | f16 padded dist tmp (~112.5MB)
    _Float16* pfg = (_Float16*)d_ws;                          // 8192 halves
    _Float16* afg = (_Float16*)((char*)d_ws + 16384);         // 8192 halves
    float* p2g = (float*)((char*)d_ws + 32768);
    float* pag = (float*)((char*)d_ws + 33280);
    float* ang = (float*)((char*)d_ws + 33792);
    _Float16* tmp = (_Float16*)((char*)d_ws + 36864);

    gyro_params_k<<<1, 128, 0, stream>>>(w, bias, pfg, afg, p2g, pag, ang);

    dim3 gD(PML / 64, NB);                        // (450, 16)
    gyro_dist_mfma_h<<<gD, 256, 0, stream>>>(x, pfg, afg, p2g, pag, ang, tmp);

    dim3 gB(4, NO, NB);                           // 8192 blocks
    gyro_box3d_h<<<gB, 256, 0, stream>>>(tmp, out, w, bias);
}

// Round 3
// 422.976 us; speedup vs baseline: 1.0363x; 1.0363x over previous
//
#include <hip/hip_runtime.h>
#include <math.h>

#define NB 16      // batch
#define NO 128     // output channels
#define ND 64      // manifold dim
#define NN 30      // grid side
#define NM 27000   // NN^3
#define PROW 32    // k-padded row length
#define PPLANE 960 // 30*PROW
#define PML 28800  // 30*PPLANE  (padded points per (b,o))

typedef _Float16 half8 __attribute__((ext_vector_type(8)));
typedef _Float16 half4 __attribute__((ext_vector_type(4)));
typedef float    f32x4 __attribute__((ext_vector_type(4)));

// ---------------------------------------------------------------------------
__device__ __forceinline__ float asinh_fast(float t) {
    return __logf(t + __builtin_amdgcn_sqrtf(t * t + 1.0f));
}

__device__ __forceinline__ float gyro_dist(float x2, float dp, float da,
                                           float p2, float pa, float an) {
    float beta  = 1.0f - p2;
    float alpha = 1.0f - 2.0f * dp + x2;
    float den   = fmaxf(1.0f - 2.0f * dp + p2 * x2, 1e-15f);
    float rden  = __builtin_amdgcn_rcpf(den);
    float sc    = (beta * da - alpha * pa) * rden;
    float dn2   = fmaxf((alpha * alpha * p2 - 2.0f * alpha * beta * dp +
                         beta * beta * x2) * (rden * rden), 1e-15f);
    float denom = fmaxf((1.0f - dn2) * an, 1e-15f);
    float t     = 2.0f * sc * __builtin_amdgcn_rcpf(denom);
    return asinh_fast(t);
}

// Param algebra collapsed to scalars of S = sum_d w[o][d]^2 (exact rewrite
// of the reference expmap0/project/transp0 chain).
__device__ __forceinline__ void param_scalars(float S, float bb,
                                              float* fp_o, float* p2_o,
                                              float* betaC_o, float* pa_o,
                                              float* an_o) {
    float sq  = sqrtf(S);
    float un  = fmaxf(fabsf(bb) * sq, 1e-15f);
    float t1  = tanhf(fminf(un, 15.0f));
    float sc1 = t1 / un;
    float gn  = fmaxf(t1, 1e-15f);
    float sc2 = (gn > 0.996f) ? (0.996f / gn) : 1.0f;
    float fp  = bb * sc1 * sc2;
    float p2  = fp * fp * S;
    float betaC = fmaxf(1.0f - p2, 1e-15f);
    *fp_o = fp; *p2_o = p2; *betaC_o = betaC;
    *pa_o = fp * betaC * S;
    *an_o = fmaxf(betaC * sq, 1e-15f);
}

// dist at origin, computed redundantly by EVERY wave (no LDS, no barrier):
// butterfly reduce of w[o][lane]^2 gives all lanes the sum.
__device__ __forceinline__ float dist0_all(const float* __restrict__ w,
                                           const float* __restrict__ bias,
                                           int o, int lane) {
    float v = w[o * ND + lane];
    float s = v * v;
#pragma unroll
    for (int off = 32; off > 0; off >>= 1) s += __shfl_xor(s, off, 64);
    float fp, p2, betaC, pa, an;
    param_scalars(s, bias[o], &fp, &p2, &betaC, &pa, &an);
    float denom = fmaxf((1.0f - fmaxf(p2, 1e-15f)) * an, 1e-15f);
    return asinh_fast(-2.0f * pa * __builtin_amdgcn_rcpf(denom));
}

// ---------------------------------------------------------------------------
// Kernel 0: per-o params -> global (f16 B-fragments + f32 scalars).
// Fragment layout matches the dist kernel's per-lane read:
//   frag[(ot8*2+h)*64 + (o&15) + 16*q] holds B[k=h*32+q*8+jj][o]
// ---------------------------------------------------------------------------
__global__ __launch_bounds__(128) void gyro_params_k(
    const float* __restrict__ w, const float* __restrict__ bias,
    _Float16* __restrict__ pfg, _Float16* __restrict__ afg,
    float* __restrict__ p2g, float* __restrict__ pag,
    float* __restrict__ ang) {
    int o = threadIdx.x;            // 128 threads, one o each
    const float* wr = w + o * ND;
    float bb = bias[o];
    float S = 0.0f;
    for (int d = 0; d < ND; ++d) S += wr[d] * wr[d];
    float fp, p2, betaC, pa, an;
    param_scalars(S, bb, &fp, &p2, &betaC, &pa, &an);
    p2g[o] = p2; pag[o] = pa; ang[o] = an;

    half8* pf8 = (half8*)pfg;
    half8* af8 = (half8*)afg;
    int ot8 = o >> 4, j = o & 15;
#pragma unroll
    for (int h = 0; h < 2; ++h)
#pragma unroll
        for (int q = 0; q < 4; ++q) {
            int d0i = h * 32 + q * 8;
            half8 hp, ha;
#pragma unroll
            for (int jj = 0; jj < 8; ++jj) {
                float wv = wr[d0i + jj];
                hp[jj] = (_Float16)(wv * fp);
                ha[jj] = (_Float16)(wv * betaC);
            }
            pf8[(ot8 * 2 + h) * 64 + j + 16 * q] = hp;
            af8[(ot8 * 2 + h) * 64 + j + 16 * q] = ha;
        }
}

// ---------------------------------------------------------------------------
// Kernel 1 (unchanged from R2, passed): dist -> f16 k-padded tmp holding the
// 3-tap K-SUM, computed in-register via wave shuffles, f32-accumulated.
// ---------------------------------------------------------------------------
__global__ __launch_bounds__(256) void gyro_dist_mfma_h(
    const float* __restrict__ x,
    const _Float16* __restrict__ pfg, const _Float16* __restrict__ afg,
    const float* __restrict__ p2g, const float* __restrict__ pag,
    const float* __restrict__ ang,
    _Float16* __restrict__ tmp) {
    __shared__ __align__(16) half8 xf[8 * 64];   // 8 KB
    __shared__ float x2p[64 * 8];
    __shared__ __align__(16) float x2_s[64];

    const int tid = threadIdx.x;
    const int mp0 = blockIdx.x * 64;
    const int b   = blockIdx.y;
    const int lane = tid & 63, wid = tid >> 6;

    // prefetch B fragments into registers (L2-hot, coalesced 16B/lane)
    const half8* pf8 = (const half8*)pfg;
    const half8* af8 = (const half8*)afg;
    half8 bp[2][2], ba[2][2];
#pragma unroll
    for (int ot = 0; ot < 2; ++ot)
#pragma unroll
        for (int h = 0; h < 2; ++h) {
            int idx = ((wid * 2 + ot) * 2 + h) * 64 + lane;
            bp[ot][h] = pf8[idx];
            ba[ot][h] = af8[idx];
        }

    // stage x tile (f32 -> f16 fragments) + |x|^2 partials
#pragma unroll
    for (int n = 0; n < 2; ++n) {
        int s = tid + n * 256;
        int f = s >> 6, l = s & 63;
        int mt = f >> 1, h = f & 1;
        int mloc = mt * 16 + (l & 15);
        int quad = l >> 4;
        int k0 = h * 32 + quad * 8;
        int gmp = mp0 + mloc;
        int kcol = gmp & 31;
        int row  = gmp >> 5;
        half8 hv;
        float part = 0.0f;
        if (kcol < 30) {
            int gm = row * 30 + kcol;
            const float4* src = (const float4*)(x + ((size_t)gm * NB + b) * ND + k0);
            float4 v0 = src[0], v1 = src[1];
            float vv[8] = {v0.x, v0.y, v0.z, v0.w, v1.x, v1.y, v1.z, v1.w};
#pragma unroll
            for (int jj = 0; jj < 8; ++jj) {
                hv[jj] = (_Float16)vv[jj];
                part += vv[jj] * vv[jj];
            }
        } else {
#pragma unroll
            for (int jj = 0; jj < 8; ++jj) hv[jj] = (_Float16)0.0f;
        }
        xf[f * 64 + l] = hv;
        x2p[mloc * 8 + h * 4 + quad] = part;
    }
    __syncthreads();
    if (tid < 64) {
        float s = 0.0f;
#pragma unroll
        for (int r = 0; r < 8; ++r) s += x2p[tid * 8 + r];
        x2_s[tid] = s;
    }
    __syncthreads();

    // MFMA: 4 m-tiles x 2 o-tiles x {p,a} x 2 k-halves
    f32x4 accp[4][2], acca[4][2];
#pragma unroll
    for (int mt = 0; mt < 4; ++mt)
#pragma unroll
        for (int ot = 0; ot < 2; ++ot) {
            accp[mt][ot] = (f32x4)0.0f;
            acca[mt][ot] = (f32x4)0.0f;
        }
#pragma unroll
    for (int h = 0; h < 2; ++h) {
        half8 afr[4];
#pragma unroll
        for (int mt = 0; mt < 4; ++mt) afr[mt] = xf[(mt * 2 + h) * 64 + lane];
#pragma unroll
        for (int mt = 0; mt < 4; ++mt)
#pragma unroll
            for (int ot = 0; ot < 2; ++ot) {
                accp[mt][ot] = __builtin_amdgcn_mfma_f32_16x16x32_f16(
                    afr[mt], bp[ot][h], accp[mt][ot], 0, 0, 0);
                acca[mt][ot] = __builtin_amdgcn_mfma_f32_16x16x32_f16(
                    afr[mt], ba[ot][h], acca[mt][ot], 0, 0, 0);
            }
    }

    // epilogue: gyro dist per element in f32, in-register 3-tap k-sum via
    // shuffles, then f16 store of 4 consecutive padded-m (8B).
    const int lo = lane & 15, quad = lane >> 4;
    const size_t obase = (size_t)(b * NO) * PML;
#pragma unroll
    for (int ot = 0; ot < 2; ++ot) {
        const int o = wid * 32 + ot * 16 + lo;
        const float P2 = p2g[o], PA = pag[o], AN = ang[o];
        const float denom0 = fmaxf((1.0f - fmaxf(P2, 1e-15f)) * AN, 1e-15f);
        const float d0 = asinh_fast(-2.0f * PA * __builtin_amdgcn_rcpf(denom0));
        float dv[4][4];
#pragma unroll
        for (int mt = 0; mt < 4; ++mt) {
            const int mb = mt * 16 + quad * 4;
            float4 x2v = *(const float4*)&x2_s[mb];
            dv[mt][0] = gyro_dist(x2v.x, accp[mt][ot][0], acca[mt][ot][0], P2, PA, AN);
            dv[mt][1] = gyro_dist(x2v.y, accp[mt][ot][1], acca[mt][ot][1], P2, PA, AN);
            dv[mt][2] = gyro_dist(x2v.z, accp[mt][ot][2], acca[mt][ot][2], P2, PA, AN);
            dv[mt][3] = gyro_dist(x2v.w, accp[mt][ot][3], acca[mt][ot][3], P2, PA, AN);
        }
#pragma unroll
        for (int mt = 0; mt < 4; ++mt) {
            float tl = __shfl_up(dv[mt][3], 16);      // lane-16: prev quad e3
            float tr = __shfl_down(dv[mt][0], 16);    // lane+16: next quad e0
            float L, R;
            if (mt & 1) {
                float tl2 = __shfl_down(dv[mt - 1][3], 48); // lane+48 (quad0 only)
                L = (quad == 0) ? tl2 : tl;
                R = (quad == 3) ? d0 : tr;            // kcol==31 pad: don't-care
            } else {
                float tr2 = __shfl_up(dv[mt + 1][0], 48);   // lane-48 (quad3 only)
                L = (quad == 0) ? d0 : tl;            // kcol==0: left pad = d0
                R = (quad == 3) ? tr2 : tr;
            }
            half4 hv;
            hv[0] = (_Float16)(L + dv[mt][0] + dv[mt][1]);
            hv[1] = (_Float16)(dv[mt][0] + dv[mt][1] + dv[mt][2]);
            hv[2] = (_Float16)(dv[mt][1] + dv[mt][2] + dv[mt][3]);
            hv[3] = (_Float16)(dv[mt][2] + dv[mt][3] + R);
            *(half4*)(tmp + obase + (size_t)o * PML + (mp0 + mt * 16 + quad * 4)) = hv;
        }
    }
}

// ---------------------------------------------------------------------------
// Kernel 2 (REWRITTEN): single-barrier streaming box. tmp holds k-pre-summed
// values; this kernel fuses the j-sum and i-sum into one register-rolling
// walk along i. Per thread: one (j, k-quad) column; jsum = 3 half4 LDS reads
// per plane (f32-accumulated); out[i] = js[i-1]+js[i]+js[i+1].
// OOB i-planes are T3-filled at load (T3 = k-sum of an all-d0 row), so the
// i-boundary value 9*d0 emerges automatically; j-boundary uses T3 consts.
// Barriers: 1. LDS: 19.2 KB (8 blocks/CU, 32 waves/CU).
// ---------------------------------------------------------------------------
__global__ __launch_bounds__(256) void gyro_box_i_h(
    const _Float16* __restrict__ tmp, float* __restrict__ dst,
    const float* __restrict__ w, const float* __restrict__ bias) {
    __shared__ __align__(16) _Float16 vol[10 * PPLANE];   // 19.2 KB

    const int tid  = threadIdx.x;
    const int lane = tid & 63;
    const int i0   = blockIdx.x * 8;
    const int o    = blockIdx.y;
    const int b    = blockIdx.z;
    const int bo   = b * NO + o;

    // every wave computes d0 redundantly -> no LDS dependency, no extra barrier
    const float d0 = dist0_all(w, bias, o, lane);
    const float T3 = 3.0f * d0;
    const _Float16 T3h = (_Float16)T3;

    // load 10 planes (120 half8 each); OOB plane -> T3 fill
    const half8* tsrc = (const half8*)(tmp + (size_t)bo * PML);
    half8* v8 = (half8*)vol;
    for (int idx = tid; idx < 1200; idx += 256) {
        int sl = idx / 120, r8 = idx - sl * 120;
        int ip = i0 - 1 + sl;
        half8 hv;
        if (ip >= 0 && ip < NN) {
            hv = tsrc[ip * 120 + r8];
        } else {
#pragma unroll
            for (int jj = 0; jj < 8; ++jj) hv[jj] = T3h;
        }
        v8[idx] = hv;
    }
    __syncthreads();

    // walk: unit = (j, g) with j in [0,30), g in [0,8) -> 240 active threads
    if (tid < 240) {
        const int j = tid >> 3, g = tid & 7;
        const half4* vb = (const half4*)vol;       // half4 index: sl*240 + jr*8 + g
        const int base = j * 8 + g;

        // jsum(sl): f32 sum over rows j-1..j+1 of the half4 at (sl, ., g)
        auto jsum = [&](int sl) -> float4 {
            const half4* pb = vb + sl * 240;
            half4 c = pb[base];
            float4 s;
            s.x = (float)c[0]; s.y = (float)c[1];
            s.z = (float)c[2]; s.w = (float)c[3];
            if (j > 0) {
                half4 u = pb[base - 8];
                s.x += (float)u[0]; s.y += (float)u[1];
                s.z += (float)u[2]; s.w += (float)u[3];
            } else {
                s.x += T3; s.y += T3; s.z += T3; s.w += T3;
            }
            if (j < NN - 1) {
                half4 dn = pb[base + 8];
                s.x += (float)dn[0]; s.y += (float)dn[1];
                s.z += (float)dn[2]; s.w += (float)dn[3];
            } else {
                s.x += T3; s.y += T3; s.z += T3; s.w += T3;
            }
            return s;
        };

        const int nout = (NN - i0 < 8) ? (NN - i0) : 8;
        float4 a = jsum(0);
        float4 bc = jsum(1);
        float* gbase = dst + (size_t)bo * NM + j * 30 + g * 4;
        for (int p = 0; p < nout; ++p) {
            float4 c = jsum(p + 2);
            float4 s;
            s.x = a.x + bc.x + c.x; s.y = a.y + bc.y + c.y;
            s.z = a.z + bc.z + c.z; s.w = a.w + bc.w + c.w;
            float* gp = gbase + (size_t)(i0 + p) * 900;
            float2 lo2; lo2.x = s.x; lo2.y = s.y;
            *(float2*)gp = lo2;                    // 8B-aligned always
            if (g < 7) {
                float2 hi2; hi2.x = s.z; hi2.y = s.w;
                *(float2*)(gp + 2) = hi2;
            }
            a = bc; bc = c;
        }
    }
}

extern "C" void kernel_launch(void* const* d_in, const int* in_sizes, int n_in,
                              void* d_out, int out_size, void* d_ws, size_t ws_size,
                              hipStream_t stream) {
    const float* x    = (const float*)d_in[0];   // (M, B, D)
    const float* w    = (const float*)d_in[1];   // (O, D)
    const float* bias = (const float*)d_in[2];   // (O, 1)
    float* out = (float*)d_out;                  // (B, O, N, N, N)

    // ws layout: pf 32KB-half | af | p2/pa/an | f16 padded k-summed tmp
    _Float16* pfg = (_Float16*)d_ws;                          // 8192 halves
    _Float16* afg = (_Float16*)((char*)d_ws + 16384);         // 8192 halves
    float* p2g = (float*)((char*)d_ws + 32768);
    float* pag = (float*)((char*)d_ws + 33280);
    float* ang = (float*)((char*)d_ws + 33792);
    _Float16* tmp = (_Float16*)((char*)d_ws + 36864);

    gyro_params_k<<<1, 128, 0, stream>>>(w, bias, pfg, afg, p2g, pag, ang);

    dim3 gD(PML / 64, NB);                        // (450, 16)
    gyro_dist_mfma_h<<<gD, 256, 0, stream>>>(x, pfg, afg, p2g, pag, ang, tmp);

    dim3 gB(4, NO, NB);                           // 8192 blocks
    gyro_box_i_h<<<gB, 256, 0, stream>>>(tmp, out, w, bias);
}

// Round 4
// 419.408 us; speedup vs baseline: 1.0451x; 1.0085x over previous
//
#include <hip/hip_runtime.h>
#include <math.h>

#define NB 16      // batch
#define NO 128     // output channels
#define ND 64      // manifold dim
#define NN 30      // grid side
#define NM 27000   // NN^3
#define PROW 32    // k-padded row length
#define PPLANE 960 // 30*PROW
#define PML 28800  // 30*PPLANE  (padded points per (b,o))

typedef _Float16 half8 __attribute__((ext_vector_type(8)));
typedef _Float16 half4 __attribute__((ext_vector_type(4)));
typedef float    f32x4 __attribute__((ext_vector_type(4)));

// ---------------------------------------------------------------------------
__device__ __forceinline__ float asinh_fast(float t) {
    return __logf(t + __builtin_amdgcn_sqrtf(t * t + 1.0f));
}

// Single-rcp rewrite (R4): t = 2(b*da - a*pa)*den / ((den^2 - num2)*an).
// Exact algebra of the two-rcp form: denom_old = (1 - num2/den^2)*an, so
// t = 2*sc/denom_old = 2*(b*da-a*pa)*den/((den^2-num2)*an). Saves one
// v_rcp_f32 + several muls per element (59M elements).
__device__ __forceinline__ float gyro_dist(float x2, float dp, float da,
                                           float p2, float pa, float an) {
    float beta  = 1.0f - p2;
    float alpha = 1.0f - 2.0f * dp + x2;
    float den   = fmaxf(1.0f - 2.0f * dp + p2 * x2, 1e-15f);
    float num2  = alpha * alpha * p2 - 2.0f * alpha * beta * dp +
                  beta * beta * x2;                    // |diff|^2 * den^2
    float g     = fmaxf(den * den - num2, 1e-15f);     // (1-dn2) * den^2
    float t     = 2.0f * (beta * da - alpha * pa) * den *
                  __builtin_amdgcn_rcpf(g * an);
    return asinh_fast(t);
}

// Param algebra collapsed to scalars of S = sum_d w[o][d]^2 (exact rewrite
// of the reference expmap0/project/transp0 chain).
__device__ __forceinline__ void param_scalars(float S, float bb,
                                              float* fp_o, float* p2_o,
                                              float* betaC_o, float* pa_o,
                                              float* an_o) {
    float sq  = sqrtf(S);
    float un  = fmaxf(fabsf(bb) * sq, 1e-15f);
    float t1  = tanhf(fminf(un, 15.0f));
    float sc1 = t1 / un;
    float gn  = fmaxf(t1, 1e-15f);
    float sc2 = (gn > 0.996f) ? (0.996f / gn) : 1.0f;
    float fp  = bb * sc1 * sc2;
    float p2  = fp * fp * S;
    float betaC = fmaxf(1.0f - p2, 1e-15f);
    *fp_o = fp; *p2_o = p2; *betaC_o = betaC;
    *pa_o = fp * betaC * S;
    *an_o = fmaxf(betaC * sq, 1e-15f);
}

// dist at origin, computed redundantly by EVERY wave (no LDS, no barrier):
// butterfly reduce of w[o][lane]^2 gives all lanes the sum.
__device__ __forceinline__ float dist0_all(const float* __restrict__ w,
                                           const float* __restrict__ bias,
                                           int o, int lane) {
    float v = w[o * ND + lane];
    float s = v * v;
#pragma unroll
    for (int off = 32; off > 0; off >>= 1) s += __shfl_xor(s, off, 64);
    float fp, p2, betaC, pa, an;
    param_scalars(s, bias[o], &fp, &p2, &betaC, &pa, &an);
    float denom = fmaxf((1.0f - fmaxf(p2, 1e-15f)) * an, 1e-15f);
    return asinh_fast(-2.0f * pa * __builtin_amdgcn_rcpf(denom));
}

// ---------------------------------------------------------------------------
// Kernel 0: per-o params -> global (f16 B-fragments + f32 scalars).
// Fragment layout matches the dist kernel's per-lane read:
//   frag[(ot8*2+h)*64 + (o&15) + 16*q] holds B[k=h*32+q*8+jj][o]
// ---------------------------------------------------------------------------
__global__ __launch_bounds__(128) void gyro_params_k(
    const float* __restrict__ w, const float* __restrict__ bias,
    _Float16* __restrict__ pfg, _Float16* __restrict__ afg,
    float* __restrict__ p2g, float* __restrict__ pag,
    float* __restrict__ ang) {
    int o = threadIdx.x;            // 128 threads, one o each
    const float* wr = w + o * ND;
    float bb = bias[o];
    float S = 0.0f;
    for (int d = 0; d < ND; ++d) S += wr[d] * wr[d];
    float fp, p2, betaC, pa, an;
    param_scalars(S, bb, &fp, &p2, &betaC, &pa, &an);
    p2g[o] = p2; pag[o] = pa; ang[o] = an;

    half8* pf8 = (half8*)pfg;
    half8* af8 = (half8*)afg;
    int ot8 = o >> 4, j = o & 15;
#pragma unroll
    for (int h = 0; h < 2; ++h)
#pragma unroll
        for (int q = 0; q < 4; ++q) {
            int d0i = h * 32 + q * 8;
            half8 hp, ha;
#pragma unroll
            for (int jj = 0; jj < 8; ++jj) {
                float wv = wr[d0i + jj];
                hp[jj] = (_Float16)(wv * fp);
                ha[jj] = (_Float16)(wv * betaC);
            }
            pf8[(ot8 * 2 + h) * 64 + j + 16 * q] = hp;
            af8[(ot8 * 2 + h) * 64 + j + 16 * q] = ha;
        }
}

// ---------------------------------------------------------------------------
// Kernel 1: dist -> f16 k-padded tmp holding the 3-tap K-SUM, computed
// in-register via wave shuffles, f32-accumulated. (Structure unchanged from
// R3-passed; only gyro_dist body changed to single-rcp form.)
// ---------------------------------------------------------------------------
__global__ __launch_bounds__(256) void gyro_dist_mfma_h(
    const float* __restrict__ x,
    const _Float16* __restrict__ pfg, const _Float16* __restrict__ afg,
    const float* __restrict__ p2g, const float* __restrict__ pag,
    const float* __restrict__ ang,
    _Float16* __restrict__ tmp) {
    __shared__ __align__(16) half8 xf[8 * 64];   // 8 KB
    __shared__ float x2p[64 * 8];
    __shared__ __align__(16) float x2_s[64];

    const int tid = threadIdx.x;
    const int mp0 = blockIdx.x * 64;
    const int b   = blockIdx.y;
    const int lane = tid & 63, wid = tid >> 6;

    // prefetch B fragments into registers (L2-hot, coalesced 16B/lane)
    const half8* pf8 = (const half8*)pfg;
    const half8* af8 = (const half8*)afg;
    half8 bp[2][2], ba[2][2];
#pragma unroll
    for (int ot = 0; ot < 2; ++ot)
#pragma unroll
        for (int h = 0; h < 2; ++h) {
            int idx = ((wid * 2 + ot) * 2 + h) * 64 + lane;
            bp[ot][h] = pf8[idx];
            ba[ot][h] = af8[idx];
        }

    // stage x tile (f32 -> f16 fragments) + |x|^2 partials
#pragma unroll
    for (int n = 0; n < 2; ++n) {
        int s = tid + n * 256;
        int f = s >> 6, l = s & 63;
        int mt = f >> 1, h = f & 1;
        int mloc = mt * 16 + (l & 15);
        int quad = l >> 4;
        int k0 = h * 32 + quad * 8;
        int gmp = mp0 + mloc;
        int kcol = gmp & 31;
        int row  = gmp >> 5;
        half8 hv;
        float part = 0.0f;
        if (kcol < 30) {
            int gm = row * 30 + kcol;
            const float4* src = (const float4*)(x + ((size_t)gm * NB + b) * ND + k0);
            float4 v0 = src[0], v1 = src[1];
            float vv[8] = {v0.x, v0.y, v0.z, v0.w, v1.x, v1.y, v1.z, v1.w};
#pragma unroll
            for (int jj = 0; jj < 8; ++jj) {
                hv[jj] = (_Float16)vv[jj];
                part += vv[jj] * vv[jj];
            }
        } else {
#pragma unroll
            for (int jj = 0; jj < 8; ++jj) hv[jj] = (_Float16)0.0f;
        }
        xf[f * 64 + l] = hv;
        x2p[mloc * 8 + h * 4 + quad] = part;
    }
    __syncthreads();
    if (tid < 64) {
        float s = 0.0f;
#pragma unroll
        for (int r = 0; r < 8; ++r) s += x2p[tid * 8 + r];
        x2_s[tid] = s;
    }
    __syncthreads();

    // MFMA: 4 m-tiles x 2 o-tiles x {p,a} x 2 k-halves
    f32x4 accp[4][2], acca[4][2];
#pragma unroll
    for (int mt = 0; mt < 4; ++mt)
#pragma unroll
        for (int ot = 0; ot < 2; ++ot) {
            accp[mt][ot] = (f32x4)0.0f;
            acca[mt][ot] = (f32x4)0.0f;
        }
#pragma unroll
    for (int h = 0; h < 2; ++h) {
        half8 afr[4];
#pragma unroll
        for (int mt = 0; mt < 4; ++mt) afr[mt] = xf[(mt * 2 + h) * 64 + lane];
#pragma unroll
        for (int mt = 0; mt < 4; ++mt)
#pragma unroll
            for (int ot = 0; ot < 2; ++ot) {
                accp[mt][ot] = __builtin_amdgcn_mfma_f32_16x16x32_f16(
                    afr[mt], bp[ot][h], accp[mt][ot], 0, 0, 0);
                acca[mt][ot] = __builtin_amdgcn_mfma_f32_16x16x32_f16(
                    afr[mt], ba[ot][h], acca[mt][ot], 0, 0, 0);
            }
    }

    // epilogue: gyro dist per element in f32, in-register 3-tap k-sum via
    // shuffles, then f16 store of 4 consecutive padded-m (8B).
    const int lo = lane & 15, quad = lane >> 4;
    const size_t obase = (size_t)(b * NO) * PML;
#pragma unroll
    for (int ot = 0; ot < 2; ++ot) {
        const int o = wid * 32 + ot * 16 + lo;
        const float P2 = p2g[o], PA = pag[o], AN = ang[o];
        const float denom0 = fmaxf((1.0f - fmaxf(P2, 1e-15f)) * AN, 1e-15f);
        const float d0 = asinh_fast(-2.0f * PA * __builtin_amdgcn_rcpf(denom0));
        float dv[4][4];
#pragma unroll
        for (int mt = 0; mt < 4; ++mt) {
            const int mb = mt * 16 + quad * 4;
            float4 x2v = *(const float4*)&x2_s[mb];
            dv[mt][0] = gyro_dist(x2v.x, accp[mt][ot][0], acca[mt][ot][0], P2, PA, AN);
            dv[mt][1] = gyro_dist(x2v.y, accp[mt][ot][1], acca[mt][ot][1], P2, PA, AN);
            dv[mt][2] = gyro_dist(x2v.z, accp[mt][ot][2], acca[mt][ot][2], P2, PA, AN);
            dv[mt][3] = gyro_dist(x2v.w, accp[mt][ot][3], acca[mt][ot][3], P2, PA, AN);
        }
#pragma unroll
        for (int mt = 0; mt < 4; ++mt) {
            float tl = __shfl_up(dv[mt][3], 16);      // lane-16: prev quad e3
            float tr = __shfl_down(dv[mt][0], 16);    // lane+16: next quad e0
            float L, R;
            if (mt & 1) {
                float tl2 = __shfl_down(dv[mt - 1][3], 48); // lane+48 (quad0 only)
                L = (quad == 0) ? tl2 : tl;
                R = (quad == 3) ? d0 : tr;            // kcol==31 pad: don't-care
            } else {
                float tr2 = __shfl_up(dv[mt + 1][0], 48);   // lane-48 (quad3 only)
                L = (quad == 0) ? d0 : tl;            // kcol==0: left pad = d0
                R = (quad == 3) ? tr2 : tr;
            }
            half4 hv;
            hv[0] = (_Float16)(L + dv[mt][0] + dv[mt][1]);
            hv[1] = (_Float16)(dv[mt][0] + dv[mt][1] + dv[mt][2]);
            hv[2] = (_Float16)(dv[mt][1] + dv[mt][2] + dv[mt][3]);
            hv[3] = (_Float16)(dv[mt][2] + dv[mt][3] + R);
            *(half4*)(tmp + obase + (size_t)o * PML + (mp0 + mt * 16 + quad * 4)) = hv;
        }
    }
}

// ---------------------------------------------------------------------------
// Kernel 2 (unchanged from R3, passed): single-barrier streaming box.
// tmp holds k-pre-summed values; j-sum + i-sum fused into one register-
// rolling walk along i. Barriers: 1. LDS: 19.2 KB (8 blocks/CU).
// ---------------------------------------------------------------------------
__global__ __launch_bounds__(256) void gyro_box_i_h(
    const _Float16* __restrict__ tmp, float* __restrict__ dst,
    const float* __restrict__ w, const float* __restrict__ bias) {
    __shared__ __align__(16) _Float16 vol[10 * PPLANE];   // 19.2 KB

    const int tid  = threadIdx.x;
    const int lane = tid & 63;
    const int i0   = blockIdx.x * 8;
    const int o    = blockIdx.y;
    const int b    = blockIdx.z;
    const int bo   = b * NO + o;

    // every wave computes d0 redundantly -> no LDS dependency, no extra barrier
    const float d0 = dist0_all(w, bias, o, lane);
    const float T3 = 3.0f * d0;
    const _Float16 T3h = (_Float16)T3;

    // load 10 planes (120 half8 each); OOB plane -> T3 fill
    const half8* tsrc = (const half8*)(tmp + (size_t)bo * PML);
    half8* v8 = (half8*)vol;
    for (int idx = tid; idx < 1200; idx += 256) {
        int sl = idx / 120, r8 = idx - sl * 120;
        int ip = i0 - 1 + sl;
        half8 hv;
        if (ip >= 0 && ip < NN) {
            hv = tsrc[ip * 120 + r8];
        } else {
#pragma unroll
            for (int jj = 0; jj < 8; ++jj) hv[jj] = T3h;
        }
        v8[idx] = hv;
    }
    __syncthreads();

    // walk: unit = (j, g) with j in [0,30), g in [0,8) -> 240 active threads
    if (tid < 240) {
        const int j = tid >> 3, g = tid & 7;
        const half4* vb = (const half4*)vol;       // half4 index: sl*240 + jr*8 + g
        const int base = j * 8 + g;

        // jsum(sl): f32 sum over rows j-1..j+1 of the half4 at (sl, ., g)
        auto jsum = [&](int sl) -> float4 {
            const half4* pb = vb + sl * 240;
            half4 c = pb[base];
            float4 s;
            s.x = (float)c[0]; s.y = (float)c[1];
            s.z = (float)c[2]; s.w = (float)c[3];
            if (j > 0) {
                half4 u = pb[base - 8];
                s.x += (float)u[0]; s.y += (float)u[1];
                s.z += (float)u[2]; s.w += (float)u[3];
            } else {
                s.x += T3; s.y += T3; s.z += T3; s.w += T3;
            }
            if (j < NN - 1) {
                half4 dn = pb[base + 8];
                s.x += (float)dn[0]; s.y += (float)dn[1];
                s.z += (float)dn[2]; s.w += (float)dn[3];
            } else {
                s.x += T3; s.y += T3; s.z += T3; s.w += T3;
            }
            return s;
        };

        const int nout = (NN - i0 < 8) ? (NN - i0) : 8;
        float4 a = jsum(0);
        float4 bc = jsum(1);
        float* gbase = dst + (size_t)bo * NM + j * 30 + g * 4;
        for (int p = 0; p < nout; ++p) {
            float4 c = jsum(p + 2);
            float4 s;
            s.x = a.x + bc.x + c.x; s.y = a.y + bc.y + c.y;
            s.z = a.z + bc.z + c.z; s.w = a.w + bc.w + c.w;
            float* gp = gbase + (size_t)(i0 + p) * 900;
            float2 lo2; lo2.x = s.x; lo2.y = s.y;
            *(float2*)gp = lo2;                    // 8B-aligned always
            if (g < 7) {
                float2 hi2; hi2.x = s.z; hi2.y = s.w;
                *(float2*)(gp + 2) = hi2;
            }
            a = bc; bc = c;
        }
    }
}

extern "C" void kernel_launch(void* const* d_in, const int* in_sizes, int n_in,
                              void* d_out, int out_size, void* d_ws, size_t ws_size,
                              hipStream_t stream) {
    const float* x    = (const float*)d_in[0];   // (M, B, D)
    const float* w    = (const float*)d_in[1];   // (O, D)
    const float* bias = (const float*)d_in[2];   // (O, 1)
    float* out = (float*)d_out;                  // (B, O, N, N, N)

    // ws layout: pf 32KB-half | af | p2/pa/an | f16 padded k-summed tmp
    _Float16* pfg = (_Float16*)d_ws;                          // 8192 halves
    _Float16* afg = (_Float16*)((char*)d_ws + 16384);         // 8192 halves
    float* p2g = (float*)((char*)d_ws + 32768);
    float* pag = (float*)((char*)d_ws + 33280);
    float* ang = (float*)((char*)d_ws + 33792);
    _Float16* tmp = (_Float16*)((char*)d_ws + 36864);

    gyro_params_k<<<1, 128, 0, stream>>>(w, bias, pfg, afg, p2g, pag, ang);

    dim3 gD(PML / 64, NB);                        // (450, 16)
    gyro_dist_mfma_h<<<gD, 256, 0, stream>>>(x, pfg, afg, p2g, pag, ang, tmp);

    dim3 gB(4, NO, NB);                           // 8192 blocks
    gyro_box_i_h<<<gB, 256, 0, stream>>>(tmp, out, w, bias);
}

// Round 7
// 408.070 us; speedup vs baseline: 1.0742x; 1.0278x over previous
//
#include <hip/hip_runtime.h>
#include <math.h>

#define NB 16      // batch
#define NO 128     // output channels
#define ND 64      // manifold dim
#define NN 30      // grid side
#define NM 27000   // NN^3
#define PROW 32    // k-padded row length
#define PPLANE 960 // 30*PROW
#define PML 28800  // 30*PPLANE  (padded points per (b,o))

typedef _Float16 half8 __attribute__((ext_vector_type(8)));
typedef _Float16 half4 __attribute__((ext_vector_type(4)));
typedef float    f32x4 __attribute__((ext_vector_type(4)));

// ---------------------------------------------------------------------------
__device__ __forceinline__ float asinh_fast(float t) {
    return __logf(t + __builtin_amdgcn_sqrtf(t * t + 1.0f));
}

// Single-rcp form (R4, passed): t = 2(b*da - a*pa)*den / ((den^2 - num2)*an).
__device__ __forceinline__ float gyro_dist(float x2, float dp, float da,
                                           float p2, float pa, float an) {
    float beta  = 1.0f - p2;
    float alpha = 1.0f - 2.0f * dp + x2;
    float den   = fmaxf(1.0f - 2.0f * dp + p2 * x2, 1e-15f);
    float num2  = alpha * alpha * p2 - 2.0f * alpha * beta * dp +
                  beta * beta * x2;                    // |diff|^2 * den^2
    float g     = fmaxf(den * den - num2, 1e-15f);     // (1-dn2) * den^2
    float t     = 2.0f * (beta * da - alpha * pa) * den *
                  __builtin_amdgcn_rcpf(g * an);
    return asinh_fast(t);
}

// Param algebra collapsed to scalars of S = sum_d w[o][d]^2 (exact rewrite
// of the reference expmap0/project/transp0 chain).
__device__ __forceinline__ void param_scalars(float S, float bb,
                                              float* fp_o, float* p2_o,
                                              float* betaC_o, float* pa_o,
                                              float* an_o) {
    float sq  = sqrtf(S);
    float un  = fmaxf(fabsf(bb) * sq, 1e-15f);
    float t1  = tanhf(fminf(un, 15.0f));
    float sc1 = t1 / un;
    float gn  = fmaxf(t1, 1e-15f);
    float sc2 = (gn > 0.996f) ? (0.996f / gn) : 1.0f;
    float fp  = bb * sc1 * sc2;
    float p2  = fp * fp * S;
    float betaC = fmaxf(1.0f - p2, 1e-15f);
    *fp_o = fp; *p2_o = p2; *betaC_o = betaC;
    *pa_o = fp * betaC * S;
    *an_o = fmaxf(betaC * sq, 1e-15f);
}

// dist at origin, computed redundantly by EVERY wave (no LDS, no barrier):
// butterfly reduce of w[o][lane]^2 gives all lanes the sum.
__device__ __forceinline__ float dist0_all(const float* __restrict__ w,
                                           const float* __restrict__ bias,
                                           int o, int lane) {
    float v = w[o * ND + lane];
    float s = v * v;
#pragma unroll
    for (int off = 32; off > 0; off >>= 1) s += __shfl_xor(s, off, 64);
    float fp, p2, betaC, pa, an;
    param_scalars(s, bias[o], &fp, &p2, &betaC, &pa, &an);
    float denom = fmaxf((1.0f - fmaxf(p2, 1e-15f)) * an, 1e-15f);
    return asinh_fast(-2.0f * pa * __builtin_amdgcn_rcpf(denom));
}

// ---------------------------------------------------------------------------
// Kernel 0 (R5): single UNSCALED w f16 fragment set + per-o scalars.
// Key identity: p = fp*w and a = betaC*w, so x.p = fp*(x.w) and
// x.a = betaC*(x.w) -- ONE dot product suffices. The dual {p,a} fragment
// sets and dual MFMA chains of R0-R4 were redundant.
// Fragment layout (unchanged): frag[(ot8*2+h)*64 + (o&15) + 16*q] holds
// w[o][k=h*32+q*8+jj] as f16.
// ---------------------------------------------------------------------------
__global__ __launch_bounds__(128) void gyro_params_k(
    const float* __restrict__ w, const float* __restrict__ bias,
    _Float16* __restrict__ wfg,
    float* __restrict__ p2g, float* __restrict__ pag,
    float* __restrict__ ang, float* __restrict__ fpg) {
    int o = threadIdx.x;            // 128 threads, one o each
    const float* wr = w + o * ND;
    float bb = bias[o];
    float S = 0.0f;
    for (int d = 0; d < ND; ++d) S += wr[d] * wr[d];
    float fp, p2, betaC, pa, an;
    param_scalars(S, bb, &fp, &p2, &betaC, &pa, &an);
    p2g[o] = p2; pag[o] = pa; ang[o] = an; fpg[o] = fp;

    half8* wf8 = (half8*)wfg;
    int ot8 = o >> 4, j = o & 15;
#pragma unroll
    for (int h = 0; h < 2; ++h)
#pragma unroll
        for (int q = 0; q < 4; ++q) {
            int d0i = h * 32 + q * 8;
            half8 hw;
#pragma unroll
            for (int jj = 0; jj < 8; ++jj)
                hw[jj] = (_Float16)wr[d0i + jj];
            wf8[(ot8 * 2 + h) * 64 + j + 16 * q] = hw;
        }
}

// ---------------------------------------------------------------------------
// Kernel 1 (R5): dist -> f16 k-padded tmp holding the 3-tap K-SUM.
// SINGLE MFMA chain (xw = x.w); dp/da derived in epilogue as fp*xw and
// betaC*xw (scales now applied in f32 AFTER the f16 dot product).
// MFMA count per 64-m tile: 16 -> 8; acc VGPRs 64 -> 32.
// ---------------------------------------------------------------------------
__global__ __launch_bounds__(256) void gyro_dist_mfma_h(
    const float* __restrict__ x,
    const _Float16* __restrict__ wfg,
    const float* __restrict__ p2g, const float* __restrict__ pag,
    const float* __restrict__ ang, const float* __restrict__ fpg,
    _Float16* __restrict__ tmp) {
    __shared__ __align__(16) half8 xf[8 * 64];   // 8 KB
    __shared__ float x2p[64 * 8];
    __shared__ __align__(16) float x2_s[64];

    const int tid = threadIdx.x;
    const int mp0 = blockIdx.x * 64;
    const int b   = blockIdx.y;
    const int lane = tid & 63, wid = tid >> 6;

    // prefetch w fragments into registers (L2-hot, coalesced 16B/lane)
    const half8* wf8 = (const half8*)wfg;
    half8 bw[2][2];
#pragma unroll
    for (int ot = 0; ot < 2; ++ot)
#pragma unroll
        for (int h = 0; h < 2; ++h)
            bw[ot][h] = wf8[((wid * 2 + ot) * 2 + h) * 64 + lane];

    // stage x tile (f32 -> f16 fragments) + |x|^2 partials
#pragma unroll
    for (int n = 0; n < 2; ++n) {
        int s = tid + n * 256;
        int f = s >> 6, l = s & 63;
        int mt = f >> 1, h = f & 1;
        int mloc = mt * 16 + (l & 15);
        int quad = l >> 4;
        int k0 = h * 32 + quad * 8;
        int gmp = mp0 + mloc;
        int kcol = gmp & 31;
        int row  = gmp >> 5;
        half8 hv;
        float part = 0.0f;
        if (kcol < 30) {
            int gm = row * 30 + kcol;
            const float4* src = (const float4*)(x + ((size_t)gm * NB + b) * ND + k0);
            float4 v0 = src[0], v1 = src[1];
            float vv[8] = {v0.x, v0.y, v0.z, v0.w, v1.x, v1.y, v1.z, v1.w};
#pragma unroll
            for (int jj = 0; jj < 8; ++jj) {
                hv[jj] = (_Float16)vv[jj];
                part += vv[jj] * vv[jj];
            }
        } else {
#pragma unroll
            for (int jj = 0; jj < 8; ++jj) hv[jj] = (_Float16)0.0f;
        }
        xf[f * 64 + l] = hv;
        x2p[mloc * 8 + h * 4 + quad] = part;
    }
    __syncthreads();
    if (tid < 64) {
        float s = 0.0f;
#pragma unroll
        for (int r = 0; r < 8; ++r) s += x2p[tid * 8 + r];
        x2_s[tid] = s;
    }
    __syncthreads();

    // MFMA: 4 m-tiles x 2 o-tiles x 2 k-halves, SINGLE chain
    f32x4 acc[4][2];
#pragma unroll
    for (int mt = 0; mt < 4; ++mt)
#pragma unroll
        for (int ot = 0; ot < 2; ++ot) acc[mt][ot] = (f32x4)0.0f;
#pragma unroll
    for (int h = 0; h < 2; ++h) {
        half8 afr[4];
#pragma unroll
        for (int mt = 0; mt < 4; ++mt) afr[mt] = xf[(mt * 2 + h) * 64 + lane];
#pragma unroll
        for (int mt = 0; mt < 4; ++mt)
#pragma unroll
            for (int ot = 0; ot < 2; ++ot)
                acc[mt][ot] = __builtin_amdgcn_mfma_f32_16x16x32_f16(
                    afr[mt], bw[ot][h], acc[mt][ot], 0, 0, 0);
    }

    // epilogue: dp = FP*xw, da = BETA*xw; gyro dist in f32; in-register
    // 3-tap k-sum via shuffles; f16 store of 4 consecutive padded-m (8B).
    const int lo = lane & 15, quad = lane >> 4;
    const size_t obase = (size_t)(b * NO) * PML;
#pragma unroll
    for (int ot = 0; ot < 2; ++ot) {
        const int o = wid * 32 + ot * 16 + lo;
        const float P2 = p2g[o], PA = pag[o], AN = ang[o], FP = fpg[o];
        const float BETA = fmaxf(1.0f - P2, 1e-15f);   // == betaC (clamped)
        const float denom0 = fmaxf((1.0f - fmaxf(P2, 1e-15f)) * AN, 1e-15f);
        const float d0 = asinh_fast(-2.0f * PA * __builtin_amdgcn_rcpf(denom0));
        float dv[4][4];
#pragma unroll
        for (int mt = 0; mt < 4; ++mt) {
            const int mb = mt * 16 + quad * 4;
            float4 x2v = *(const float4*)&x2_s[mb];
#pragma unroll
            for (int e = 0; e < 4; ++e) {
                float xw = acc[mt][ot][e];
                float x2e = (e == 0) ? x2v.x : (e == 1) ? x2v.y
                          : (e == 2) ? x2v.z : x2v.w;
                dv[mt][e] = gyro_dist(x2e, FP * xw, BETA * xw, P2, PA, AN);
            }
        }
#pragma unroll
        for (int mt = 0; mt < 4; ++mt) {
            float tl = __shfl_up(dv[mt][3], 16);      // lane-16: prev quad e3
            float tr = __shfl_down(dv[mt][0], 16);    // lane+16: next quad e0
            float L, R;
            if (mt & 1) {
                float tl2 = __shfl_down(dv[mt - 1][3], 48); // lane+48 (quad0 only)
                L = (quad == 0) ? tl2 : tl;
                R = (quad == 3) ? d0 : tr;            // kcol==31 pad: don't-care
            } else {
                float tr2 = __shfl_up(dv[mt + 1][0], 48);   // lane-48 (quad3 only)
                L = (quad == 0) ? d0 : tl;            // kcol==0: left pad = d0
                R = (quad == 3) ? tr2 : tr;
            }
            half4 hv;
            hv[0] = (_Float16)(L + dv[mt][0] + dv[mt][1]);
            hv[1] = (_Float16)(dv[mt][0] + dv[mt][1] + dv[mt][2]);
            hv[2] = (_Float16)(dv[mt][1] + dv[mt][2] + dv[mt][3]);
            hv[3] = (_Float16)(dv[mt][2] + dv[mt][3] + R);
            *(half4*)(tmp + obase + (size_t)o * PML + (mp0 + mt * 16 + quad * 4)) = hv;
        }
    }
}

// ---------------------------------------------------------------------------
// Kernel 2 (unchanged from R3, passed): single-barrier streaming box.
// tmp holds k-pre-summed values; j-sum + i-sum fused into one register-
// rolling walk along i. Barriers: 1. LDS: 19.2 KB (8 blocks/CU).
// ---------------------------------------------------------------------------
__global__ __launch_bounds__(256) void gyro_box_i_h(
    const _Float16* __restrict__ tmp, float* __restrict__ dst,
    const float* __restrict__ w, const float* __restrict__ bias) {
    __shared__ __align__(16) _Float16 vol[10 * PPLANE];   // 19.2 KB

    const int tid  = threadIdx.x;
    const int lane = tid & 63;
    const int i0   = blockIdx.x * 8;
    const int o    = blockIdx.y;
    const int b    = blockIdx.z;
    const int bo   = b * NO + o;

    // every wave computes d0 redundantly -> no LDS dependency, no extra barrier
    const float d0 = dist0_all(w, bias, o, lane);
    const float T3 = 3.0f * d0;
    const _Float16 T3h = (_Float16)T3;

    // load 10 planes (120 half8 each); OOB plane -> T3 fill
    const half8* tsrc = (const half8*)(tmp + (size_t)bo * PML);
    half8* v8 = (half8*)vol;
    for (int idx = tid; idx < 1200; idx += 256) {
        int sl = idx / 120, r8 = idx - sl * 120;
        int ip = i0 - 1 + sl;
        half8 hv;
        if (ip >= 0 && ip < NN) {
            hv = tsrc[ip * 120 + r8];
        } else {
#pragma unroll
            for (int jj = 0; jj < 8; ++jj) hv[jj] = T3h;
        }
        v8[idx] = hv;
    }
    __syncthreads();

    // walk: unit = (j, g) with j in [0,30), g in [0,8) -> 240 active threads
    if (tid < 240) {
        const int j = tid >> 3, g = tid & 7;
        const half4* vb = (const half4*)vol;       // half4 index: sl*240 + jr*8 + g
        const int base = j * 8 + g;

        // jsum(sl): f32 sum over rows j-1..j+1 of the half4 at (sl, ., g)
        auto jsum = [&](int sl) -> float4 {
            const half4* pb = vb + sl * 240;
            half4 c = pb[base];
            float4 s;
            s.x = (float)c[0]; s.y = (float)c[1];
            s.z = (float)c[2]; s.w = (float)c[3];
            if (j > 0) {
                half4 u = pb[base - 8];
                s.x += (float)u[0]; s.y += (float)u[1];
                s.z += (float)u[2]; s.w += (float)u[3];
            } else {
                s.x += T3; s.y += T3; s.z += T3; s.w += T3;
            }
            if (j < NN - 1) {
                half4 dn = pb[base + 8];
                s.x += (float)dn[0]; s.y += (float)dn[1];
                s.z += (float)dn[2]; s.w += (float)dn[3];
            } else {
                s.x += T3; s.y += T3; s.z += T3; s.w += T3;
            }
            return s;
        };

        const int nout = (NN - i0 < 8) ? (NN - i0) : 8;
        float4 a = jsum(0);
        float4 bc = jsum(1);
        float* gbase = dst + (size_t)bo * NM + j * 30 + g * 4;
        for (int p = 0; p < nout; ++p) {
            float4 c = jsum(p + 2);
            float4 s;
            s.x = a.x + bc.x + c.x; s.y = a.y + bc.y + c.y;
            s.z = a.z + bc.z + c.z; s.w = a.w + bc.w + c.w;
            float* gp = gbase + (size_t)(i0 + p) * 900;
            float2 lo2; lo2.x = s.x; lo2.y = s.y;
            *(float2*)gp = lo2;                    // 8B-aligned always
            if (g < 7) {
                float2 hi2; hi2.x = s.z; hi2.y = s.w;
                *(float2*)(gp + 2) = hi2;
            }
            a = bc; bc = c;
        }
    }
}

extern "C" void kernel_launch(void* const* d_in, const int* in_sizes, int n_in,
                              void* d_out, int out_size, void* d_ws, size_t ws_size,
                              hipStream_t stream) {
    const float* x    = (const float*)d_in[0];   // (M, B, D)
    const float* w    = (const float*)d_in[1];   // (O, D)
    const float* bias = (const float*)d_in[2];   // (O, 1)
    float* out = (float*)d_out;                  // (B, O, N, N, N)

    // ws layout: wf 16KB | (gap) | p2/pa/an/fp scalars | f16 k-summed tmp
    _Float16* wfg = (_Float16*)d_ws;                          // 8192 halves
    float* p2g = (float*)((char*)d_ws + 32768);
    float* pag = (float*)((char*)d_ws + 33280);
    float* ang = (float*)((char*)d_ws + 33792);
    float* fpg = (float*)((char*)d_ws + 34304);
    _Float16* tmp = (_Float16*)((char*)d_ws + 36864);

    gyro_params_k<<<1, 128, 0, stream>>>(w, bias, wfg, p2g, pag, ang, fpg);

    dim3 gD(PML / 64, NB);                        // (450, 16)
    gyro_dist_mfma_h<<<gD, 256, 0, stream>>>(x, wfg, p2g, pag, ang, fpg, tmp);

    dim3 gB(4, NO, NB);                           // 8192 blocks
    gyro_box_i_h<<<gB, 256, 0, stream>>>(tmp, out, w, bias);
}

// Round 8
// 405.928 us; speedup vs baseline: 1.0799x; 1.0053x over previous
//
#include <hip/hip_runtime.h>
#include <math.h>

#define NB 16      // batch
#define NO 128     // output channels
#define ND 64      // manifold dim
#define NN 30      // grid side
#define NM 27000   // NN^3
#define PROW 32    // k-padded row length
#define PPLANE 960 // 30*PROW
#define PML 28800  // 30*PPLANE  (padded points per (b,o))
#define NSLAB 15   // i-planes per box block (R8: 8 -> 15, cuts seam overfetch)
#define NPL 17     // loaded planes per box block (NSLAB + 2 halo)

typedef _Float16 half8 __attribute__((ext_vector_type(8)));
typedef _Float16 half4 __attribute__((ext_vector_type(4)));
typedef float    f32x4 __attribute__((ext_vector_type(4)));

// ---------------------------------------------------------------------------
__device__ __forceinline__ float asinh_fast(float t) {
    return __logf(t + __builtin_amdgcn_sqrtf(t * t + 1.0f));
}

// Single-rcp form (R4, passed): t = 2(b*da - a*pa)*den / ((den^2 - num2)*an).
__device__ __forceinline__ float gyro_dist(float x2, float dp, float da,
                                           float p2, float pa, float an) {
    float beta  = 1.0f - p2;
    float alpha = 1.0f - 2.0f * dp + x2;
    float den   = fmaxf(1.0f - 2.0f * dp + p2 * x2, 1e-15f);
    float num2  = alpha * alpha * p2 - 2.0f * alpha * beta * dp +
                  beta * beta * x2;                    // |diff|^2 * den^2
    float g     = fmaxf(den * den - num2, 1e-15f);     // (1-dn2) * den^2
    float t     = 2.0f * (beta * da - alpha * pa) * den *
                  __builtin_amdgcn_rcpf(g * an);
    return asinh_fast(t);
}

// Param algebra collapsed to scalars of S = sum_d w[o][d]^2 (exact rewrite
// of the reference expmap0/project/transp0 chain).
__device__ __forceinline__ void param_scalars(float S, float bb,
                                              float* fp_o, float* p2_o,
                                              float* betaC_o, float* pa_o,
                                              float* an_o) {
    float sq  = sqrtf(S);
    float un  = fmaxf(fabsf(bb) * sq, 1e-15f);
    float t1  = tanhf(fminf(un, 15.0f));
    float sc1 = t1 / un;
    float gn  = fmaxf(t1, 1e-15f);
    float sc2 = (gn > 0.996f) ? (0.996f / gn) : 1.0f;
    float fp  = bb * sc1 * sc2;
    float p2  = fp * fp * S;
    float betaC = fmaxf(1.0f - p2, 1e-15f);
    *fp_o = fp; *p2_o = p2; *betaC_o = betaC;
    *pa_o = fp * betaC * S;
    *an_o = fmaxf(betaC * sq, 1e-15f);
}

// dist at origin, computed redundantly by EVERY wave (no LDS, no barrier):
// butterfly reduce of w[o][lane]^2 gives all lanes the sum.
__device__ __forceinline__ float dist0_all(const float* __restrict__ w,
                                           const float* __restrict__ bias,
                                           int o, int lane) {
    float v = w[o * ND + lane];
    float s = v * v;
#pragma unroll
    for (int off = 32; off > 0; off >>= 1) s += __shfl_xor(s, off, 64);
    float fp, p2, betaC, pa, an;
    param_scalars(s, bias[o], &fp, &p2, &betaC, &pa, &an);
    float denom = fmaxf((1.0f - fmaxf(p2, 1e-15f)) * an, 1e-15f);
    return asinh_fast(-2.0f * pa * __builtin_amdgcn_rcpf(denom));
}

// ---------------------------------------------------------------------------
// Kernel 0 (R5, passed): single UNSCALED w f16 fragment set + per-o scalars.
// p = fp*w and a = betaC*w, so ONE dot product x.w suffices.
// Fragment layout: frag[(ot8*2+h)*64 + (o&15) + 16*q] holds
// w[o][k=h*32+q*8+jj] as f16.
// ---------------------------------------------------------------------------
__global__ __launch_bounds__(128) void gyro_params_k(
    const float* __restrict__ w, const float* __restrict__ bias,
    _Float16* __restrict__ wfg,
    float* __restrict__ p2g, float* __restrict__ pag,
    float* __restrict__ ang, float* __restrict__ fpg) {
    int o = threadIdx.x;            // 128 threads, one o each
    const float* wr = w + o * ND;
    float bb = bias[o];
    float S = 0.0f;
    for (int d = 0; d < ND; ++d) S += wr[d] * wr[d];
    float fp, p2, betaC, pa, an;
    param_scalars(S, bb, &fp, &p2, &betaC, &pa, &an);
    p2g[o] = p2; pag[o] = pa; ang[o] = an; fpg[o] = fp;

    half8* wf8 = (half8*)wfg;
    int ot8 = o >> 4, j = o & 15;
#pragma unroll
    for (int h = 0; h < 2; ++h)
#pragma unroll
        for (int q = 0; q < 4; ++q) {
            int d0i = h * 32 + q * 8;
            half8 hw;
#pragma unroll
            for (int jj = 0; jj < 8; ++jj)
                hw[jj] = (_Float16)wr[d0i + jj];
            wf8[(ot8 * 2 + h) * 64 + j + 16 * q] = hw;
        }
}

// ---------------------------------------------------------------------------
// Kernel 1 (R5, passed): dist -> f16 k-padded tmp holding the 3-tap K-SUM.
// SINGLE MFMA chain (xw = x.w); dp/da derived in epilogue as fp*xw and
// betaC*xw (scales applied in f32 AFTER the f16 dot product).
// ---------------------------------------------------------------------------
__global__ __launch_bounds__(256) void gyro_dist_mfma_h(
    const float* __restrict__ x,
    const _Float16* __restrict__ wfg,
    const float* __restrict__ p2g, const float* __restrict__ pag,
    const float* __restrict__ ang, const float* __restrict__ fpg,
    _Float16* __restrict__ tmp) {
    __shared__ __align__(16) half8 xf[8 * 64];   // 8 KB
    __shared__ float x2p[64 * 8];
    __shared__ __align__(16) float x2_s[64];

    const int tid = threadIdx.x;
    const int mp0 = blockIdx.x * 64;
    const int b   = blockIdx.y;
    const int lane = tid & 63, wid = tid >> 6;

    // prefetch w fragments into registers (L2-hot, coalesced 16B/lane)
    const half8* wf8 = (const half8*)wfg;
    half8 bw[2][2];
#pragma unroll
    for (int ot = 0; ot < 2; ++ot)
#pragma unroll
        for (int h = 0; h < 2; ++h)
            bw[ot][h] = wf8[((wid * 2 + ot) * 2 + h) * 64 + lane];

    // stage x tile (f32 -> f16 fragments) + |x|^2 partials
#pragma unroll
    for (int n = 0; n < 2; ++n) {
        int s = tid + n * 256;
        int f = s >> 6, l = s & 63;
        int mt = f >> 1, h = f & 1;
        int mloc = mt * 16 + (l & 15);
        int quad = l >> 4;
        int k0 = h * 32 + quad * 8;
        int gmp = mp0 + mloc;
        int kcol = gmp & 31;
        int row  = gmp >> 5;
        half8 hv;
        float part = 0.0f;
        if (kcol < 30) {
            int gm = row * 30 + kcol;
            const float4* src = (const float4*)(x + ((size_t)gm * NB + b) * ND + k0);
            float4 v0 = src[0], v1 = src[1];
            float vv[8] = {v0.x, v0.y, v0.z, v0.w, v1.x, v1.y, v1.z, v1.w};
#pragma unroll
            for (int jj = 0; jj < 8; ++jj) {
                hv[jj] = (_Float16)vv[jj];
                part += vv[jj] * vv[jj];
            }
        } else {
#pragma unroll
            for (int jj = 0; jj < 8; ++jj) hv[jj] = (_Float16)0.0f;
        }
        xf[f * 64 + l] = hv;
        x2p[mloc * 8 + h * 4 + quad] = part;
    }
    __syncthreads();
    if (tid < 64) {
        float s = 0.0f;
#pragma unroll
        for (int r = 0; r < 8; ++r) s += x2p[tid * 8 + r];
        x2_s[tid] = s;
    }
    __syncthreads();

    // MFMA: 4 m-tiles x 2 o-tiles x 2 k-halves, SINGLE chain
    f32x4 acc[4][2];
#pragma unroll
    for (int mt = 0; mt < 4; ++mt)
#pragma unroll
        for (int ot = 0; ot < 2; ++ot) acc[mt][ot] = (f32x4)0.0f;
#pragma unroll
    for (int h = 0; h < 2; ++h) {
        half8 afr[4];
#pragma unroll
        for (int mt = 0; mt < 4; ++mt) afr[mt] = xf[(mt * 2 + h) * 64 + lane];
#pragma unroll
        for (int mt = 0; mt < 4; ++mt)
#pragma unroll
            for (int ot = 0; ot < 2; ++ot)
                acc[mt][ot] = __builtin_amdgcn_mfma_f32_16x16x32_f16(
                    afr[mt], bw[ot][h], acc[mt][ot], 0, 0, 0);
    }

    // epilogue: dp = FP*xw, da = BETA*xw; gyro dist in f32; in-register
    // 3-tap k-sum via shuffles; f16 store of 4 consecutive padded-m (8B).
    const int lo = lane & 15, quad = lane >> 4;
    const size_t obase = (size_t)(b * NO) * PML;
#pragma unroll
    for (int ot = 0; ot < 2; ++ot) {
        const int o = wid * 32 + ot * 16 + lo;
        const float P2 = p2g[o], PA = pag[o], AN = ang[o], FP = fpg[o];
        const float BETA = fmaxf(1.0f - P2, 1e-15f);   // == betaC (clamped)
        const float denom0 = fmaxf((1.0f - fmaxf(P2, 1e-15f)) * AN, 1e-15f);
        const float d0 = asinh_fast(-2.0f * PA * __builtin_amdgcn_rcpf(denom0));
        float dv[4][4];
#pragma unroll
        for (int mt = 0; mt < 4; ++mt) {
            const int mb = mt * 16 + quad * 4;
            float4 x2v = *(const float4*)&x2_s[mb];
#pragma unroll
            for (int e = 0; e < 4; ++e) {
                float xw = acc[mt][ot][e];
                float x2e = (e == 0) ? x2v.x : (e == 1) ? x2v.y
                          : (e == 2) ? x2v.z : x2v.w;
                dv[mt][e] = gyro_dist(x2e, FP * xw, BETA * xw, P2, PA, AN);
            }
        }
#pragma unroll
        for (int mt = 0; mt < 4; ++mt) {
            float tl = __shfl_up(dv[mt][3], 16);      // lane-16: prev quad e3
            float tr = __shfl_down(dv[mt][0], 16);    // lane+16: next quad e0
            float L, R;
            if (mt & 1) {
                float tl2 = __shfl_down(dv[mt - 1][3], 48); // lane+48 (quad0 only)
                L = (quad == 0) ? tl2 : tl;
                R = (quad == 3) ? d0 : tr;            // kcol==31 pad: don't-care
            } else {
                float tr2 = __shfl_up(dv[mt + 1][0], 48);   // lane-48 (quad3 only)
                L = (quad == 0) ? d0 : tl;            // kcol==0: left pad = d0
                R = (quad == 3) ? tr2 : tr;
            }
            half4 hv;
            hv[0] = (_Float16)(L + dv[mt][0] + dv[mt][1]);
            hv[1] = (_Float16)(dv[mt][0] + dv[mt][1] + dv[mt][2]);
            hv[2] = (_Float16)(dv[mt][1] + dv[mt][2] + dv[mt][3]);
            hv[3] = (_Float16)(dv[mt][2] + dv[mt][3] + R);
            *(half4*)(tmp + obase + (size_t)o * PML + (mp0 + mt * 16 + quad * 4)) = hv;
        }
    }
}

// ---------------------------------------------------------------------------
// Kernel 2 (R8): streaming box with NSLAB=15 (was 8). Seam overfetch drops
// from 8/30 to 2/30 planes per (b,o). LDS 17 planes = 32.6 KB (4 blocks/CU).
// Structure otherwise identical to R3-passed version: single barrier,
// register-rolling j+i sum walk.
// ---------------------------------------------------------------------------
__global__ __launch_bounds__(256) void gyro_box_i_h(
    const _Float16* __restrict__ tmp, float* __restrict__ dst,
    const float* __restrict__ w, const float* __restrict__ bias) {
    __shared__ __align__(16) _Float16 vol[NPL * PPLANE];   // 32.64 KB

    const int tid  = threadIdx.x;
    const int lane = tid & 63;
    const int i0   = blockIdx.x * NSLAB;
    const int o    = blockIdx.y;
    const int b    = blockIdx.z;
    const int bo   = b * NO + o;

    // every wave computes d0 redundantly -> no LDS dependency, no extra barrier
    const float d0 = dist0_all(w, bias, o, lane);
    const float T3 = 3.0f * d0;
    const _Float16 T3h = (_Float16)T3;

    // load NPL planes (120 half8 each); OOB plane -> T3 fill
    const half8* tsrc = (const half8*)(tmp + (size_t)bo * PML);
    half8* v8 = (half8*)vol;
    for (int idx = tid; idx < NPL * 120; idx += 256) {
        int sl = idx / 120, r8 = idx - sl * 120;
        int ip = i0 - 1 + sl;
        half8 hv;
        if (ip >= 0 && ip < NN) {
            hv = tsrc[ip * 120 + r8];
        } else {
#pragma unroll
            for (int jj = 0; jj < 8; ++jj) hv[jj] = T3h;
        }
        v8[idx] = hv;
    }
    __syncthreads();

    // walk: unit = (j, g) with j in [0,30), g in [0,8) -> 240 active threads
    if (tid < 240) {
        const int j = tid >> 3, g = tid & 7;
        const half4* vb = (const half4*)vol;       // half4 index: sl*240 + jr*8 + g
        const int base = j * 8 + g;

        // jsum(sl): f32 sum over rows j-1..j+1 of the half4 at (sl, ., g)
        auto jsum = [&](int sl) -> float4 {
            const half4* pb = vb + sl * 240;
            half4 c = pb[base];
            float4 s;
            s.x = (float)c[0]; s.y = (float)c[1];
            s.z = (float)c[2]; s.w = (float)c[3];
            if (j > 0) {
                half4 u = pb[base - 8];
                s.x += (float)u[0]; s.y += (float)u[1];
                s.z += (float)u[2]; s.w += (float)u[3];
            } else {
                s.x += T3; s.y += T3; s.z += T3; s.w += T3;
            }
            if (j < NN - 1) {
                half4 dn = pb[base + 8];
                s.x += (float)dn[0]; s.y += (float)dn[1];
                s.z += (float)dn[2]; s.w += (float)dn[3];
            } else {
                s.x += T3; s.y += T3; s.z += T3; s.w += T3;
            }
            return s;
        };

        const int nout = (NN - i0 < NSLAB) ? (NN - i0) : NSLAB;
        float4 a = jsum(0);
        float4 bc = jsum(1);
        float* gbase = dst + (size_t)bo * NM + j * 30 + g * 4;
        for (int p = 0; p < nout; ++p) {
            float4 c = jsum(p + 2);
            float4 s;
            s.x = a.x + bc.x + c.x; s.y = a.y + bc.y + c.y;
            s.z = a.z + bc.z + c.z; s.w = a.w + bc.w + c.w;
            float* gp = gbase + (size_t)(i0 + p) * 900;
            float2 lo2; lo2.x = s.x; lo2.y = s.y;
            *(float2*)gp = lo2;                    // 8B-aligned always
            if (g < 7) {
                float2 hi2; hi2.x = s.z; hi2.y = s.w;
                *(float2*)(gp + 2) = hi2;
            }
            a = bc; bc = c;
        }
    }
}

extern "C" void kernel_launch(void* const* d_in, const int* in_sizes, int n_in,
                              void* d_out, int out_size, void* d_ws, size_t ws_size,
                              hipStream_t stream) {
    const float* x    = (const float*)d_in[0];   // (M, B, D)
    const float* w    = (const float*)d_in[1];   // (O, D)
    const float* bias = (const float*)d_in[2];   // (O, 1)
    float* out = (float*)d_out;                  // (B, O, N, N, N)

    // ws layout: wf 16KB | (gap) | p2/pa/an/fp scalars | f16 k-summed tmp
    _Float16* wfg = (_Float16*)d_ws;                          // 8192 halves
    float* p2g = (float*)((char*)d_ws + 32768);
    float* pag = (float*)((char*)d_ws + 33280);
    float* ang = (float*)((char*)d_ws + 33792);
    float* fpg = (float*)((char*)d_ws + 34304);
    _Float16* tmp = (_Float16*)((char*)d_ws + 36864);

    gyro_params_k<<<1, 128, 0, stream>>>(w, bias, wfg, p2g, pag, ang, fpg);

    dim3 gD(PML / 64, NB);                        // (450, 16)
    gyro_dist_mfma_h<<<gD, 256, 0, stream>>>(x, wfg, p2g, pag, ang, fpg, tmp);

    dim3 gB(2, NO, NB);                           // 4096 blocks (slab=15)
    gyro_box_i_h<<<gB, 256, 0, stream>>>(tmp, out, w, bias);
}